// Round 1
// baseline (1979.333 us; speedup 1.0000x reference)
//
#include <hip/hip_runtime.h>

#define B_   8
#define N_   1024
#define F0_  56
#define D_   70
#define D2_  72      // padded row stride for h/hA (288B, 16B-aligned)
#define DFC_ 128
#define LSTR 76      // LDS row stride (stride%8==4 words -> conflict-free b128)
#define NEG_BIG (-9e15f)

// ---------------------------------------------------------------- featem
__global__ __launch_bounds__(128) void featem_kernel(
    const float* __restrict__ H, const float* __restrict__ W, float* __restrict__ x)
{
  const int r = blockIdx.x, t = threadIdx.x;
  __shared__ float row[F0_];
  if (t < F0_) row[t] = H[(size_t)r * F0_ + t];
  __syncthreads();
  if (t < D_) {
    float a = 0.f;
#pragma unroll 8
    for (int m = 0; m < F0_; m++) a += row[m] * W[t * F0_ + m];
    x[(size_t)r * D_ + t] = a;
  }
}

// ------------------------------------------------- h = x@W^T / hA = h@A
// mode 0: out[r][d] = sum_m in[r][m] * W[d*D+m]   (x @ W^T)
// mode 1: out[r][d] = sum_m in[r][m] * W[m*D+d]   (h @ A)
__global__ __launch_bounds__(128) void gatmm_kernel(
    const float* __restrict__ in, int in_stride, const float* __restrict__ W,
    int mode, float* __restrict__ out)
{
  const int r = blockIdx.x, t = threadIdx.x;
  __shared__ float row[D_];
  if (t < D_) row[t] = in[(size_t)r * in_stride + t];
  __syncthreads();
  if (t < D2_) {
    float a = 0.f;
    if (t < D_) {
      if (mode == 0) {
#pragma unroll 7
        for (int m = 0; m < D_; m++) a += row[m] * W[t * D_ + m];
      } else {
#pragma unroll 7
        for (int m = 0; m < D_; m++) a += row[m] * W[m * D_ + t];
      }
    }
    out[(size_t)r * D2_ + t] = a;  // cols 70,71 zero-padded
  }
}

// ------------------------------------------- pass1: online softmax stats
// e_jk = hA_j . h_k + hA_k . h_j ; stats over j (axis=1) per column k,
// simultaneously for mask A2r (rbf+A1) and mask A1. j range chunked by 4.
__global__ __launch_bounds__(256) void pass1_kernel(
    const float* __restrict__ hg, const float* __restrict__ hAg,
    const float* __restrict__ A1, const float* __restrict__ A2,
    const float* __restrict__ mup, const float* __restrict__ devp,
    float* __restrict__ M1p, float* __restrict__ S1p,
    float* __restrict__ M2p, float* __restrict__ S2p)
{
  const int kt = blockIdx.x;   // 0..31 column tile
  const int jc = blockIdx.y;   // 0..3  j chunk
  const int b  = blockIdx.z;   // 0..7
  const int tid = threadIdx.x;
  const int kl = tid & 31, jl = tid >> 5;   // jl 0..7
  const int k0 = kt * 32;

  __shared__ __align__(16) float hk[32][LSTR], hAk[32][LSTR];
  const float* hb  = hg  + (size_t)b * N_ * D2_;
  const float* hAb = hAg + (size_t)b * N_ * D2_;
  for (int idx = tid; idx < 32 * D2_; idx += 256) {
    int r = idx / D2_, c = idx - r * D2_;
    hk[r][c]  = hb[(size_t)(k0 + r) * D2_ + c];
    hAk[r][c] = hAb[(size_t)(k0 + r) * D2_ + c];
  }
  __syncthreads();

  const float mu = mup[0], idev = 1.0f / devp[0];
  float M1 = -3.0e38f, S1 = 0.f, M2 = -3.0e38f, S2 = 0.f;
  const int jbase = jc * (N_ / 4);
  const float* A1c = A1 + (size_t)b * N_ * N_ + k0 + kl;
  const float* A2c = A2 + (size_t)b * N_ * N_ + k0 + kl;

  for (int jj = jl; jj < N_ / 4; jj += 8) {
    const int j = jbase + jj;
    const float4* hj  = (const float4*)(hb  + (size_t)j * D2_);
    const float4* hAj = (const float4*)(hAb + (size_t)j * D2_);
    float e1 = 0.f, e2 = 0.f;
#pragma unroll 6
    for (int m4 = 0; m4 < D2_ / 4; m4++) {
      float4 a   = hAj[m4];
      float4 hkv = *(const float4*)&hk[kl][m4 * 4];
      float4 ha  = *(const float4*)&hAk[kl][m4 * 4];
      float4 hjv = hj[m4];
      e1 += a.x * hkv.x + a.y * hkv.y + a.z * hkv.z + a.w * hkv.w;
      e2 += ha.x * hjv.x + ha.y * hjv.y + ha.z * hjv.z + ha.w * hjv.w;
    }
    const float e = e1 + e2;
    const float a1 = A1c[(size_t)j * N_];
    const float a2 = A2c[(size_t)j * N_];
    const float rbf = (a2 <= 10.f) ? __expf(-(a2 - mu) * (a2 - mu) * idev) : 0.f;
    const float adj1 = rbf + a1;                     // A2r value
    const float m1 = (adj1 > 0.f) ? e : NEG_BIG;
    const float m2 = (a1  > 0.f) ? e : NEG_BIG;
    if (m1 > M1) { S1 = S1 * __expf(M1 - m1) + 1.f; M1 = m1; } else { S1 += __expf(m1 - M1); }
    if (m2 > M2) { S2 = S2 * __expf(M2 - m2) + 1.f; M2 = m2; } else { S2 += __expf(m2 - M2); }
  }

  __shared__ float rM[8][32], rS[8][32];
  rM[jl][kl] = M1; rS[jl][kl] = S1;
  __syncthreads();
  if (tid < 32) {
    float M = rM[0][tid], S = rS[0][tid];
    for (int q = 1; q < 8; q++) {
      float m = rM[q][tid], s = rS[q][tid];
      float nM = fmaxf(M, m);
      S = S * __expf(M - nM) + s * __expf(m - nM);
      M = nM;
    }
    M1p[((size_t)b * 4 + jc) * N_ + k0 + tid] = M;
    S1p[((size_t)b * 4 + jc) * N_ + k0 + tid] = S;
  }
  __syncthreads();
  rM[jl][kl] = M2; rS[jl][kl] = S2;
  __syncthreads();
  if (tid < 32) {
    float M = rM[0][tid], S = rS[0][tid];
    for (int q = 1; q < 8; q++) {
      float m = rM[q][tid], s = rS[q][tid];
      float nM = fmaxf(M, m);
      S = S * __expf(M - nM) + s * __expf(m - nM);
      M = nM;
    }
    M2p[((size_t)b * 4 + jc) * N_ + k0 + tid] = M;
    S2p[((size_t)b * 4 + jc) * N_ + k0 + tid] = S;
  }
}

// merge the 4 j-chunk partials
__global__ __launch_bounds__(256) void finalize_kernel(
    const float* __restrict__ M1p, const float* __restrict__ S1p,
    const float* __restrict__ M2p, const float* __restrict__ S2p,
    float* __restrict__ M1, float* __restrict__ S1,
    float* __restrict__ M2, float* __restrict__ S2)
{
  int idx = blockIdx.x * 256 + threadIdx.x;
  if (idx >= B_ * N_) return;
  int b = idx >> 10, k = idx & (N_ - 1);
  {
    float M = -3.0e38f, S = 0.f;
    for (int q = 0; q < 4; q++) {
      float m = M1p[((size_t)b * 4 + q) * N_ + k], s = S1p[((size_t)b * 4 + q) * N_ + k];
      float nM = fmaxf(M, m);
      S = S * __expf(M - nM) + s * __expf(m - nM); M = nM;
    }
    M1[idx] = M; S1[idx] = S;
  }
  {
    float M = -3.0e38f, S = 0.f;
    for (int q = 0; q < 4; q++) {
      float m = M2p[((size_t)b * 4 + q) * N_ + k], s = S2p[((size_t)b * 4 + q) * N_ + k];
      float nM = fmaxf(M, m);
      S = S * __expf(M - nM) + s * __expf(m - nM); M = nM;
    }
    M2[idx] = M; S2[idx] = S;
  }
}

// ------------------------------------------- pass2: hp1/hp2 aggregation
__global__ __launch_bounds__(256) void pass2_kernel(
    const float* __restrict__ hg, const float* __restrict__ hAg,
    const float* __restrict__ A1, const float* __restrict__ A2,
    const float* __restrict__ mup, const float* __restrict__ devp,
    const float* __restrict__ M1, const float* __restrict__ S1,
    const float* __restrict__ M2, const float* __restrict__ S2,
    float* __restrict__ hp1, float* __restrict__ hp2)
{
  const int it = blockIdx.x;  // 0..63 row tile (16 rows)
  const int b  = blockIdx.y;
  const int i0 = it * 16;
  const int tid = threadIdx.x;

  __shared__ __align__(16) float hi[16][LSTR], hAi[16][LSTR];
  __shared__ __align__(16) float hj[32][LSTR], hAj[32][LSTR];
  __shared__ float w1[16][33], w2[16][33];

  const float* hb  = hg  + (size_t)b * N_ * D2_;
  const float* hAb = hAg + (size_t)b * N_ * D2_;
  for (int idx = tid; idx < 16 * D2_; idx += 256) {
    int r = idx / D2_, c = idx - r * D2_;
    hi[r][c]  = hb[(size_t)(i0 + r) * D2_ + c];
    hAi[r][c] = hAb[(size_t)(i0 + r) * D2_ + c];
  }

  const float mu = mup[0], idev = 1.0f / devp[0];
  const int ie = tid >> 5, je = tid & 31;   // e-phase mapping
  const int dg = tid & 15, ila = tid >> 4;  // accumulate mapping
  float acc1[5] = {0, 0, 0, 0, 0}, acc2[5] = {0, 0, 0, 0, 0};
  const float* Mc1 = M1 + (size_t)b * N_;
  const float* Sc1 = S1 + (size_t)b * N_;
  const float* Mc2 = M2 + (size_t)b * N_;
  const float* Sc2 = S2 + (size_t)b * N_;

  for (int jt = 0; jt < N_; jt += 32) {
    __syncthreads();  // prev iter consumers done (also covers hi/hAi load)
    for (int idx = tid; idx < 32 * D2_; idx += 256) {
      int r = idx / D2_, c = idx - r * D2_;
      hj[r][c]  = hb[(size_t)(jt + r) * D2_ + c];
      hAj[r][c] = hAb[(size_t)(jt + r) * D2_ + c];
    }
    __syncthreads();
#pragma unroll
    for (int q = 0; q < 2; q++) {
      const int ier = ie + q * 8;
      float e1 = 0.f, e2 = 0.f;
#pragma unroll 6
      for (int m4 = 0; m4 < D2_ / 4; m4++) {
        float4 a   = *(const float4*)&hAi[ier][m4 * 4];
        float4 hv  = *(const float4*)&hj[je][m4 * 4];
        float4 aj  = *(const float4*)&hAj[je][m4 * 4];
        float4 hiv = *(const float4*)&hi[ier][m4 * 4];
        e1 += a.x * hv.x + a.y * hv.y + a.z * hv.z + a.w * hv.w;
        e2 += aj.x * hiv.x + aj.y * hiv.y + aj.z * hiv.z + aj.w * hiv.w;
      }
      const float e = e1 + e2;
      const int i = i0 + ier, j = jt + je;
      const float a1 = A1[((size_t)b * N_ + i) * N_ + j];
      const float a2 = A2[((size_t)b * N_ + i) * N_ + j];
      const float rbf = (a2 <= 10.f) ? __expf(-(a2 - mu) * (a2 - mu) * idev) : 0.f;
      const float adj1 = rbf + a1;
      float wv1 = 0.f, wv2 = 0.f;
      if (adj1 > 0.f) wv1 = __expf(e - Mc1[j]) * adj1 / Sc1[j];
      if (a1  > 0.f) wv2 = __expf(e - Mc2[j]) * a1  / Sc2[j];
      w1[ier][je] = wv1; w2[ier][je] = wv2;
    }
    __syncthreads();
    if (dg < 14) {
      for (int j = 0; j < 32; j++) {
        const float f1 = w1[ila][j], f2 = w2[ila][j];
#pragma unroll
        for (int dd = 0; dd < 5; dd++) {
          const float hv = hj[j][dg * 5 + dd];
          acc1[dd] = fmaf(f1, hv, acc1[dd]);
          acc2[dd] = fmaf(f2, hv, acc2[dd]);
        }
      }
    }
  }
  if (dg < 14) {
    const int i = i0 + ila;
#pragma unroll
    for (int dd = 0; dd < 5; dd++) {
      const int d = dg * 5 + dd;
      hp1[((size_t)b * N_ + i) * D_ + d] = fmaxf(acc1[dd], 0.f);
      hp2[((size_t)b * N_ + i) * D_ + d] = fmaxf(acc2[dd], 0.f);
    }
  }
}

// ------------------------------------------- gating + layer combine
__global__ __launch_bounds__(64) void combine_kernel(
    const float* __restrict__ x, const float* __restrict__ hp1, const float* __restrict__ hp2,
    const float* __restrict__ g1, const float* __restrict__ g2w, const float* __restrict__ g2b,
    float* __restrict__ xn)
{
  const int r = blockIdx.x, t = threadIdx.x;
  const float* xr = x + (size_t)r * D_;
  const float* p1 = hp1 + (size_t)r * D_;
  const float* p2 = hp2 + (size_t)r * D_;
  float x0 = xr[t], a0 = p1[t], b0 = p2[t];
  float d1 = x0 * g1[t], d2 = a0 * g2w[t], d3 = b0 * g2w[t];
  float x1 = 0.f, a1v = 0.f, b1v = 0.f;
  if (t < D_ - 64) {
    x1 = xr[64 + t]; a1v = p1[64 + t]; b1v = p2[64 + t];
    d1 += x1 * g1[64 + t]; d2 += a1v * g2w[64 + t]; d3 += b1v * g2w[64 + t];
  }
#pragma unroll
  for (int off = 1; off < 64; off <<= 1) {
    d1 += __shfl_xor(d1, off);
    d2 += __shfl_xor(d2, off);
    d3 += __shfl_xor(d3, off);
  }
  const float bb = g2b[0];
  const float c1 = 1.f / (1.f + __expf(-(d1 + d2 + bb)));
  const float c2 = 1.f / (1.f + __expf(-(d1 + d3 + bb)));
  xn[(size_t)r * D_ + t] = (c1 * x0 + (1.f - c1) * a0) - (c2 * x0 + (1.f - c2) * b0);
  if (t < D_ - 64)
    xn[(size_t)r * D_ + 64 + t] =
        (c1 * x1 + (1.f - c1) * a1v) - (c2 * x1 + (1.f - c2) * b1v);
}

// ------------------------------------------- masked sum pool over N
__global__ __launch_bounds__(256) void pool_kernel(
    const float* __restrict__ x, const float* __restrict__ V, float* __restrict__ pooled)
{
  const int d = blockIdx.x, b = blockIdx.y, t = threadIdx.x;
  const float* xb = x + (size_t)b * N_ * D_;
  const float* Vb = V + (size_t)b * N_;
  float s = 0.f;
  for (int n = t; n < N_; n += 256) s += xb[(size_t)n * D_ + d] * Vb[n];
#pragma unroll
  for (int off = 32; off >= 1; off >>= 1) s += __shfl_down(s, off);
  __shared__ float red[4];
  if ((t & 63) == 0) red[t >> 6] = s;
  __syncthreads();
  if (t == 0) pooled[b * D_ + d] = red[0] + red[1] + red[2] + red[3];
}

// ------------------------------------------- MLP head (single block)
__global__ __launch_bounds__(256) void fc_kernel(
    const float* __restrict__ pooled,
    const float* __restrict__ w0, const float* __restrict__ b0,
    const float* __restrict__ w1, const float* __restrict__ b1,
    const float* __restrict__ w2, const float* __restrict__ b2,
    const float* __restrict__ w3, const float* __restrict__ b3,
    float* __restrict__ out)
{
  __shared__ float pin[B_][D_];
  __shared__ float bufA[B_][DFC_], bufB[B_][DFC_];
  const int t = threadIdx.x;
  for (int idx = t; idx < B_ * D_; idx += 256) pin[idx / D_][idx % D_] = pooled[idx];
  __syncthreads();
  for (int idx = t; idx < B_ * DFC_; idx += 256) {
    int r = idx >> 7, o = idx & 127;
    float a = b0[o];
    for (int m = 0; m < D_; m++) a += pin[r][m] * w0[o * D_ + m];
    bufA[r][o] = fmaxf(a, 0.f);
  }
  __syncthreads();
  for (int idx = t; idx < B_ * DFC_; idx += 256) {
    int r = idx >> 7, o = idx & 127;
    float a = b1[o];
    for (int m = 0; m < DFC_; m++) a += bufA[r][m] * w1[o * DFC_ + m];
    bufB[r][o] = fmaxf(a, 0.f);
  }
  __syncthreads();
  for (int idx = t; idx < B_ * DFC_; idx += 256) {
    int r = idx >> 7, o = idx & 127;
    float a = b2[o];
    for (int m = 0; m < DFC_; m++) a += bufB[r][m] * w2[o * DFC_ + m];
    bufA[r][o] = fmaxf(a, 0.f);
  }
  __syncthreads();
  if (t < B_) {
    float a = b3[0];
    for (int m = 0; m < DFC_; m++) a += bufA[t][m] * w3[m];
    out[t] = 1.f / (1.f + __expf(-a));
  }
}

// ----------------------------------------------------------------------
extern "C" void kernel_launch(void* const* d_in, const int* in_sizes, int n_in,
                              void* d_out, int out_size, void* d_ws, size_t ws_size,
                              hipStream_t stream)
{
  const float* H     = (const float*)d_in[0];
  const float* A1    = (const float*)d_in[1];
  const float* A2    = (const float*)d_in[2];
  const float* V     = (const float*)d_in[3];
  const float* few   = (const float*)d_in[4];
  const float* mup   = (const float*)d_in[5];
  const float* devp  = (const float*)d_in[6];
  const float* gW    = (const float*)d_in[7];
  const float* gA    = (const float*)d_in[8];
  const float* g1    = (const float*)d_in[9];
  const float* g2w   = (const float*)d_in[10];
  const float* g2b   = (const float*)d_in[11];
  const float* w0 = (const float*)d_in[12]; const float* b0 = (const float*)d_in[13];
  const float* w1 = (const float*)d_in[14]; const float* b1 = (const float*)d_in[15];
  const float* w2 = (const float*)d_in[16]; const float* b2 = (const float*)d_in[17];
  const float* w3 = (const float*)d_in[18]; const float* b3 = (const float*)d_in[19];
  float* outp = (float*)d_out;

  float* ws = (float*)d_ws;
  const size_t needed = 3637808ull * sizeof(float);
  if (ws_size < needed) return;  // fail loudly (wrong output) rather than corrupt

  float* x    = ws;                  // B*N*70
  float* xn   = ws + 573440;         // B*N*70
  float* h    = ws + 1146880;        // B*N*72
  float* hA   = ws + 1736704;        // B*N*72
  float* hp1  = ws + 2326528;        // B*N*70
  float* hp2  = ws + 2899968;        // B*N*70
  float* M1   = ws + 3473408;        // B*N
  float* S1   = M1 + 8192;
  float* M2   = S1 + 8192;
  float* S2   = M2 + 8192;
  float* M1p  = S2 + 8192;           // 4*B*N each
  float* S1p  = M1p + 32768;
  float* M2p  = S1p + 32768;
  float* S2p  = M2p + 32768;
  float* pooled = S2p + 32768;       // B*70

  const int ROWS = B_ * N_;
  featem_kernel<<<ROWS, 128, 0, stream>>>(H, few, x);

  float* xcur = x;
  float* xnxt = xn;
  for (int k = 0; k < 4; k++) {
    const float* Wk  = gW  + (size_t)k * D_ * D_;
    const float* Ak  = gA  + (size_t)k * D_ * D_;
    const float* g1k = g1  + (size_t)k * D_;
    const float* g2k = g2w + (size_t)k * D_;
    const float* gbk = g2b + k;
    gatmm_kernel<<<ROWS, 128, 0, stream>>>(xcur, D_, Wk, 0, h);
    gatmm_kernel<<<ROWS, 128, 0, stream>>>(h, D2_, Ak, 1, hA);
    pass1_kernel<<<dim3(32, 4, 8), 256, 0, stream>>>(h, hA, A1, A2, mup, devp,
                                                     M1p, S1p, M2p, S2p);
    finalize_kernel<<<(B_ * N_ + 255) / 256, 256, 0, stream>>>(M1p, S1p, M2p, S2p,
                                                               M1, S1, M2, S2);
    pass2_kernel<<<dim3(64, 8), 256, 0, stream>>>(h, hA, A1, A2, mup, devp,
                                                  M1, S1, M2, S2, hp1, hp2);
    combine_kernel<<<ROWS, 64, 0, stream>>>(xcur, hp1, hp2, g1k, g2k, gbk, xnxt);
    float* tmp = xcur; xcur = xnxt; xnxt = tmp;
  }

  pool_kernel<<<dim3(D_, B_), 256, 0, stream>>>(xcur, V, pooled);
  fc_kernel<<<1, 256, 0, stream>>>(pooled, w0, b0, w1, b1, w2, b2, w3, b3, outp);
}

// Round 2
// 503.197 us; speedup vs baseline: 3.9335x; 3.9335x over previous
//
#include <hip/hip_runtime.h>

#define B_   8
#define N_   1024
#define F0_  56
#define D_   70
#define D2_  72      // fp32 h row stride
#define DK_  96      // bf16 K-padded row stride (3 x 32)
#define DFC_ 128
#define NEG_BIG (-9e15f)

typedef __attribute__((ext_vector_type(8))) short bf16x8;
typedef __attribute__((ext_vector_type(4))) float f32x4;

__device__ __forceinline__ short f2bf(float x) {
  unsigned u = __builtin_bit_cast(unsigned, x);
  u += 0x7FFF + ((u >> 16) & 1);
  return (short)(u >> 16);
}

// ---------------------------------------------------------------- featem
__global__ __launch_bounds__(128) void featem_kernel(
    const float* __restrict__ H, const float* __restrict__ W, float* __restrict__ x)
{
  const int r = blockIdx.x, t = threadIdx.x;
  __shared__ float row[F0_];
  if (t < F0_) row[t] = H[(size_t)r * F0_ + t];
  __syncthreads();
  if (t < D_) {
    float a = 0.f;
#pragma unroll 8
    for (int m = 0; m < F0_; m++) a += row[m] * W[t * F0_ + m];
    x[(size_t)r * D_ + t] = a;
  }
}

// --------------------------------------------- h = x@W^T (+f32 +bf16)
__global__ __launch_bounds__(128) void gatmm0_kernel(
    const float* __restrict__ x, const float* __restrict__ W,
    float* __restrict__ h, short* __restrict__ hb16)
{
  const int r = blockIdx.x, t = threadIdx.x;
  __shared__ float row[D_];
  if (t < D_) row[t] = x[(size_t)r * D_ + t];
  __syncthreads();
  float a = 0.f;
  if (t < D_) {
#pragma unroll 7
    for (int m = 0; m < D_; m++) a += row[m] * W[t * D_ + m];
  }
  if (t < D2_) h[(size_t)r * D2_ + t] = (t < D_) ? a : 0.f;
  if (t < DK_) hb16[(size_t)r * DK_ + t] = f2bf((t < D_) ? a : 0.f);
}

// --------------------------------------------- hA = h@A (bf16 only)
__global__ __launch_bounds__(128) void gatmm1_kernel(
    const float* __restrict__ h, const float* __restrict__ A, short* __restrict__ hAb16)
{
  const int r = blockIdx.x, t = threadIdx.x;
  __shared__ float row[D_];
  if (t < D_) row[t] = h[(size_t)r * D2_ + t];
  __syncthreads();
  float a = 0.f;
  if (t < D_) {
#pragma unroll 7
    for (int m = 0; m < D_; m++) a += row[m] * A[m * D_ + t];
  }
  if (t < DK_) hAb16[(size_t)r * DK_ + t] = f2bf((t < D_) ? a : 0.f);
}

// --------------------------------------------- hT16[b][96][N] = h^T bf16
__global__ __launch_bounds__(256) void transpose_kernel(
    const float* __restrict__ h, short* __restrict__ hT)
{
  const int nt = blockIdx.x, b = blockIdx.y, tid = threadIdx.x;
  __shared__ float tile[64][73];
  for (int idx = tid; idx < 64 * D2_; idx += 256) {
    int rr = idx / D2_, c = idx - rr * D2_;
    tile[rr][c] = h[((size_t)b * N_ + nt * 64 + rr) * D2_ + c];
  }
  __syncthreads();
  for (int idx = tid; idx < DK_ * 64; idx += 256) {
    int d = idx >> 6, nn = idx & 63;
    float v = (d < D_) ? tile[nn][d] : 0.f;
    hT[((size_t)b * DK_ + d) * N_ + nt * 64 + nn] = f2bf(v);
  }
}

// ------------------------------------------- pass1: online softmax stats (MFMA)
// grid: (32 j-tiles, 4 i-chunks, B), 256 thr (4 waves)
__global__ __launch_bounds__(256) void pass1_mfma(
    const short* __restrict__ hb16, const short* __restrict__ hAb16,
    const float* __restrict__ A1, const float* __restrict__ A2,
    const float* __restrict__ mup, const float* __restrict__ devp,
    float* __restrict__ M1p, float* __restrict__ S1p,
    float* __restrict__ M2p, float* __restrict__ S2p)
{
  const int jt = blockIdx.x, ic = blockIdx.y, b = blockIdx.z;
  const int tid = threadIdx.x, w = tid >> 6, lane = tid & 63;
  const int lr = lane & 15, kg = lane >> 4;
  const int ih = w >> 1, jh = w & 1;
  const int j0 = jt * 32;
  const short* hb  = hb16  + (size_t)b * N_ * DK_;
  const short* hAb = hAb16 + (size_t)b * N_ * DK_;

  bf16x8 b_h[3], b_hA[3];
  {
    const short* p = hb  + (size_t)(j0 + jh * 16 + lr) * DK_ + kg * 8;
    const short* q = hAb + (size_t)(j0 + jh * 16 + lr) * DK_ + kg * 8;
#pragma unroll
    for (int ks = 0; ks < 3; ks++) {
      b_h[ks]  = *(const bf16x8*)(p + ks * 32);
      b_hA[ks] = *(const bf16x8*)(q + ks * 32);
    }
  }
  const float mu = mup[0], idev = 1.0f / devp[0];
  const int jcol = j0 + jh * 16 + lr;
  float M1r = -3.0e38f, S1r = 0.f, M2r = -3.0e38f, S2r = 0.f;
  const int ibase = ic * (N_ / 4);

  for (int itl = 0; itl < N_ / 4; itl += 32) {
    const int i0 = ibase + itl + ih * 16;
    const short* pa = hAb + (size_t)(i0 + lr) * DK_ + kg * 8;
    const short* ph = hb  + (size_t)(i0 + lr) * DK_ + kg * 8;
    bf16x8 a_hA[3], a_h[3];
#pragma unroll
    for (int ks = 0; ks < 3; ks++) {
      a_hA[ks] = *(const bf16x8*)(pa + ks * 32);
      a_h[ks]  = *(const bf16x8*)(ph + ks * 32);
    }
    f32x4 E = {0.f, 0.f, 0.f, 0.f};
#pragma unroll
    for (int ks = 0; ks < 3; ks++)
      E = __builtin_amdgcn_mfma_f32_16x16x32_bf16(a_hA[ks], b_h[ks], E, 0, 0, 0);
#pragma unroll
    for (int ks = 0; ks < 3; ks++)
      E = __builtin_amdgcn_mfma_f32_16x16x32_bf16(a_h[ks], b_hA[ks], E, 0, 0, 0);

    const float* A1p = A1 + ((size_t)b * N_ + i0 + kg * 4) * N_ + jcol;
    const float* A2p = A2 + ((size_t)b * N_ + i0 + kg * 4) * N_ + jcol;
#pragma unroll
    for (int r = 0; r < 4; r++) {
      const float a1 = A1p[(size_t)r * N_];
      const float a2 = A2p[(size_t)r * N_];
      const float rbf = (a2 <= 10.f) ? __expf(-(a2 - mu) * (a2 - mu) * idev) : 0.f;
      const float adj1 = rbf + a1;
      const float e = E[r];
      const float m1 = (adj1 > 0.f) ? e : NEG_BIG;
      const float m2 = (a1  > 0.f) ? e : NEG_BIG;
      if (m1 > M1r) { S1r = S1r * __expf(M1r - m1) + 1.f; M1r = m1; } else { S1r += __expf(m1 - M1r); }
      if (m2 > M2r) { S2r = S2r * __expf(M2r - m2) + 1.f; M2r = m2; } else { S2r += __expf(m2 - M2r); }
    }
  }
  // merge across kg lane-groups (i direction)
#pragma unroll
  for (int off = 16; off <= 32; off <<= 1) {
    float Mo = __shfl_xor(M1r, off), So = __shfl_xor(S1r, off);
    float nM = fmaxf(M1r, Mo);
    S1r = S1r * __expf(M1r - nM) + So * __expf(Mo - nM); M1r = nM;
    Mo = __shfl_xor(M2r, off); So = __shfl_xor(S2r, off);
    nM = fmaxf(M2r, Mo);
    S2r = S2r * __expf(M2r - nM) + So * __expf(Mo - nM); M2r = nM;
  }
  __shared__ float sM[2][4][16], sS[2][4][16];
  if (lane < 16) {
    sM[0][w][lr] = M1r; sS[0][w][lr] = S1r;
    sM[1][w][lr] = M2r; sS[1][w][lr] = S2r;
  }
  __syncthreads();
  if (tid < 32) {
    const int jhh = tid >> 4, l2 = tid & 15;
    const size_t o = ((size_t)b * 4 + ic) * N_ + j0 + jhh * 16 + l2;
    {
      float Ma = sM[0][jhh][l2], Sa = sS[0][jhh][l2];
      float Mb = sM[0][2 + jhh][l2], Sb = sS[0][2 + jhh][l2];
      float nM = fmaxf(Ma, Mb);
      float S = Sa * __expf(Ma - nM) + Sb * __expf(Mb - nM);
      M1p[o] = nM; S1p[o] = S;
    }
    {
      float Ma = sM[1][jhh][l2], Sa = sS[1][jhh][l2];
      float Mb = sM[1][2 + jhh][l2], Sb = sS[1][2 + jhh][l2];
      float nM = fmaxf(Ma, Mb);
      float S = Sa * __expf(Ma - nM) + Sb * __expf(Mb - nM);
      M2p[o] = nM; S2p[o] = S;
    }
  }
}

// merge the 4 i-chunk partials
__global__ __launch_bounds__(256) void finalize_kernel(
    const float* __restrict__ M1p, const float* __restrict__ S1p,
    const float* __restrict__ M2p, const float* __restrict__ S2p,
    float* __restrict__ M1, float* __restrict__ S1,
    float* __restrict__ M2, float* __restrict__ S2)
{
  int idx = blockIdx.x * 256 + threadIdx.x;
  if (idx >= B_ * N_) return;
  int b = idx >> 10, k = idx & (N_ - 1);
  {
    float M = -3.0e38f, S = 0.f;
    for (int q = 0; q < 4; q++) {
      float m = M1p[((size_t)b * 4 + q) * N_ + k], s = S1p[((size_t)b * 4 + q) * N_ + k];
      float nM = fmaxf(M, m);
      S = S * __expf(M - nM) + s * __expf(m - nM); M = nM;
    }
    M1[idx] = M; S1[idx] = S;
  }
  {
    float M = -3.0e38f, S = 0.f;
    for (int q = 0; q < 4; q++) {
      float m = M2p[((size_t)b * 4 + q) * N_ + k], s = S2p[((size_t)b * 4 + q) * N_ + k];
      float nM = fmaxf(M, m);
      S = S * __expf(M - nM) + s * __expf(m - nM); M = nM;
    }
    M2[idx] = M; S2[idx] = S;
  }
}

// ------------------------------------------- pass2: E + PV via MFMA
// grid: (32 i-tiles, JC, B), 256 thr (4 waves). njt = (N/32)/JC j-tiles each.
__global__ __launch_bounds__(256) void pass2_mfma(
    const short* __restrict__ hb16, const short* __restrict__ hAb16,
    const short* __restrict__ hT16,
    const float* __restrict__ A1, const float* __restrict__ A2,
    const float* __restrict__ mup, const float* __restrict__ devp,
    const float* __restrict__ M1, const float* __restrict__ S1,
    const float* __restrict__ M2, const float* __restrict__ S2,
    float* __restrict__ hp1p, float* __restrict__ hp2p, int njt)
{
  const int it = blockIdx.x, jc = blockIdx.y, b = blockIdx.z;
  const int tid = threadIdx.x, w = tid >> 6, lane = tid & 63;
  const int lr = lane & 15, kg = lane >> 4;
  const int ih = w >> 1, jh = w & 1;
  const int i0 = it * 32;
  const int dbase = (w & 1) * 3;

  const short* hb  = hb16  + (size_t)b * N_ * DK_;
  const short* hAb = hAb16 + (size_t)b * N_ * DK_;
  const short* hTb = hT16  + (size_t)b * DK_ * N_;

  bf16x8 a_hA[3], a_h[3];
  {
    const short* pa = hAb + (size_t)(i0 + ih * 16 + lr) * DK_ + kg * 8;
    const short* ph = hb  + (size_t)(i0 + ih * 16 + lr) * DK_ + kg * 8;
#pragma unroll
    for (int ks = 0; ks < 3; ks++) {
      a_hA[ks] = *(const bf16x8*)(pa + ks * 32);
      a_h[ks]  = *(const bf16x8*)(ph + ks * 32);
    }
  }
  const float mu = mup[0], idev = 1.0f / devp[0];
  f32x4 acc[2][3];
#pragma unroll
  for (int m = 0; m < 2; m++)
#pragma unroll
    for (int q = 0; q < 3; q++) acc[m][q] = (f32x4){0.f, 0.f, 0.f, 0.f};

  __shared__ short wlds[2][32][40];  // stride 40 bf16 (80B): <=2-way banks
  const int j0base = jc * njt * 32;

  for (int t = 0; t < njt; ++t) {
    const int j0 = j0base + t * 32;
    bf16x8 b_h[3], b_hA[3];
    {
      const short* p = hb  + (size_t)(j0 + jh * 16 + lr) * DK_ + kg * 8;
      const short* q = hAb + (size_t)(j0 + jh * 16 + lr) * DK_ + kg * 8;
#pragma unroll
      for (int ks = 0; ks < 3; ks++) {
        b_h[ks]  = *(const bf16x8*)(p + ks * 32);
        b_hA[ks] = *(const bf16x8*)(q + ks * 32);
      }
    }
    f32x4 E = {0.f, 0.f, 0.f, 0.f};
#pragma unroll
    for (int ks = 0; ks < 3; ks++)
      E = __builtin_amdgcn_mfma_f32_16x16x32_bf16(a_hA[ks], b_h[ks], E, 0, 0, 0);
#pragma unroll
    for (int ks = 0; ks < 3; ks++)
      E = __builtin_amdgcn_mfma_f32_16x16x32_bf16(a_h[ks], b_hA[ks], E, 0, 0, 0);

    const int jcol = j0 + jh * 16 + lr;
    const float M1j = M1[(size_t)b * N_ + jcol];
    const float is1 = 1.0f / S1[(size_t)b * N_ + jcol];
    const float M2j = M2[(size_t)b * N_ + jcol];
    const float is2 = 1.0f / S2[(size_t)b * N_ + jcol];
    const float* A1p = A1 + ((size_t)b * N_ + i0 + ih * 16 + kg * 4) * N_ + jcol;
    const float* A2p = A2 + ((size_t)b * N_ + i0 + ih * 16 + kg * 4) * N_ + jcol;
    float w1v[4], w2v[4];
#pragma unroll
    for (int r = 0; r < 4; r++) {
      const float a1 = A1p[(size_t)r * N_];
      const float a2 = A2p[(size_t)r * N_];
      const float rbf = (a2 <= 10.f) ? __expf(-(a2 - mu) * (a2 - mu) * idev) : 0.f;
      const float adj1 = rbf + a1;
      const float e = E[r];
      w1v[r] = (adj1 > 0.f) ? __expf(e - M1j) * adj1 * is1 : 0.f;
      w2v[r] = (a1  > 0.f) ? __expf(e - M2j) * a1  * is2 : 0.f;
    }
    __syncthreads();  // prev-iter PV reads of wlds done
#pragma unroll
    for (int r = 0; r < 4; r++) {
      wlds[0][ih * 16 + kg * 4 + r][jh * 16 + lr] = f2bf(w1v[r]);
      wlds[1][ih * 16 + kg * 4 + r][jh * 16 + lr] = f2bf(w2v[r]);
    }
    __syncthreads();
    // PV: hp[i][d] += w[i][j] * hT[d][j]
    bf16x8 bt[3];
#pragma unroll
    for (int q = 0; q < 3; q++) {
      const int dt = dbase + q;
      bt[q] = *(const bf16x8*)(hTb + (size_t)(dt * 16 + lr) * N_ + j0 + kg * 8);
    }
#pragma unroll
    for (int m = 0; m < 2; m++) {
      bf16x8 af = *(const bf16x8*)&wlds[m][ih * 16 + lr][kg * 8];
#pragma unroll
      for (int q = 0; q < 3; q++)
        acc[m][q] = __builtin_amdgcn_mfma_f32_16x16x32_bf16(af, bt[q], acc[m][q], 0, 0, 0);
    }
  }
  // store partials: D layout row=i (kg*4+r), col=d (lr)
#pragma unroll
  for (int m = 0; m < 2; m++) {
#pragma unroll
    for (int q = 0; q < 3; q++) {
      const int dt = dbase + q;
      if (dt < 5) {
        float* dst = (m ? hp2p : hp1p) +
            (((size_t)jc * B_ + b) * N_ + i0 + ih * 16 + kg * 4) * 80 + dt * 16 + lr;
#pragma unroll
        for (int r = 0; r < 4; r++) dst[(size_t)r * 80] = acc[m][q][r];
      }
    }
  }
}

// ------------------------------------------- gating + layer combine (+partial sum, relu)
__global__ __launch_bounds__(64) void combine_kernel(
    const float* __restrict__ x,
    const float* __restrict__ hp1p, const float* __restrict__ hp2p, int JC,
    const float* __restrict__ g1, const float* __restrict__ g2w,
    const float* __restrict__ g2b, float* __restrict__ xn)
{
  const int r = blockIdx.x, t = threadIdx.x;
  const float* xr = x + (size_t)r * D_;
  float s1a = 0.f, s2a = 0.f, s1b = 0.f, s2b = 0.f;
  for (int q = 0; q < JC; q++) {
    const size_t base = ((size_t)q * B_ * N_ + r) * 80;
    s1a += hp1p[base + t]; s2a += hp2p[base + t];
    if (t < D_ - 64) { s1b += hp1p[base + 64 + t]; s2b += hp2p[base + 64 + t]; }
  }
  const float a0 = fmaxf(s1a, 0.f), b0 = fmaxf(s2a, 0.f);
  const float a1v = fmaxf(s1b, 0.f), b1v = fmaxf(s2b, 0.f);
  const float x0 = xr[t];
  float d1 = x0 * g1[t], d2 = a0 * g2w[t], d3 = b0 * g2w[t];
  float x1 = 0.f;
  if (t < D_ - 64) {
    x1 = xr[64 + t];
    d1 += x1 * g1[64 + t]; d2 += a1v * g2w[64 + t]; d3 += b1v * g2w[64 + t];
  }
#pragma unroll
  for (int off = 1; off < 64; off <<= 1) {
    d1 += __shfl_xor(d1, off);
    d2 += __shfl_xor(d2, off);
    d3 += __shfl_xor(d3, off);
  }
  const float bb = g2b[0];
  const float c1 = 1.f / (1.f + __expf(-(d1 + d2 + bb)));
  const float c2 = 1.f / (1.f + __expf(-(d1 + d3 + bb)));
  xn[(size_t)r * D_ + t] = (c1 * x0 + (1.f - c1) * a0) - (c2 * x0 + (1.f - c2) * b0);
  if (t < D_ - 64)
    xn[(size_t)r * D_ + 64 + t] =
        (c1 * x1 + (1.f - c1) * a1v) - (c2 * x1 + (1.f - c2) * b1v);
}

// ------------------------------------------- masked sum pool over N
__global__ __launch_bounds__(256) void pool_kernel(
    const float* __restrict__ x, const float* __restrict__ V, float* __restrict__ pooled)
{
  const int d = blockIdx.x, b = blockIdx.y, t = threadIdx.x;
  const float* xb = x + (size_t)b * N_ * D_;
  const float* Vb = V + (size_t)b * N_;
  float s = 0.f;
  for (int n = t; n < N_; n += 256) s += xb[(size_t)n * D_ + d] * Vb[n];
#pragma unroll
  for (int off = 32; off >= 1; off >>= 1) s += __shfl_down(s, off);
  __shared__ float red[4];
  if ((t & 63) == 0) red[t >> 6] = s;
  __syncthreads();
  if (t == 0) pooled[b * D_ + d] = red[0] + red[1] + red[2] + red[3];
}

// ------------------------------------------- MLP head (single block)
__global__ __launch_bounds__(256) void fc_kernel(
    const float* __restrict__ pooled,
    const float* __restrict__ w0, const float* __restrict__ b0,
    const float* __restrict__ w1, const float* __restrict__ b1,
    const float* __restrict__ w2, const float* __restrict__ b2,
    const float* __restrict__ w3, const float* __restrict__ b3,
    float* __restrict__ out)
{
  __shared__ float pin[B_][D_];
  __shared__ float bufA[B_][DFC_], bufB[B_][DFC_];
  const int t = threadIdx.x;
  for (int idx = t; idx < B_ * D_; idx += 256) pin[idx / D_][idx % D_] = pooled[idx];
  __syncthreads();
  for (int idx = t; idx < B_ * DFC_; idx += 256) {
    int r = idx >> 7, o = idx & 127;
    float a = b0[o];
    for (int m = 0; m < D_; m++) a += pin[r][m] * w0[o * D_ + m];
    bufA[r][o] = fmaxf(a, 0.f);
  }
  __syncthreads();
  for (int idx = t; idx < B_ * DFC_; idx += 256) {
    int r = idx >> 7, o = idx & 127;
    float a = b1[o];
    for (int m = 0; m < DFC_; m++) a += bufA[r][m] * w1[o * DFC_ + m];
    bufB[r][o] = fmaxf(a, 0.f);
  }
  __syncthreads();
  for (int idx = t; idx < B_ * DFC_; idx += 256) {
    int r = idx >> 7, o = idx & 127;
    float a = b2[o];
    for (int m = 0; m < DFC_; m++) a += bufB[r][m] * w2[o * DFC_ + m];
    bufA[r][o] = fmaxf(a, 0.f);
  }
  __syncthreads();
  if (t < B_) {
    float a = b3[0];
    for (int m = 0; m < DFC_; m++) a += bufA[t][m] * w3[m];
    out[t] = 1.f / (1.f + __expf(-a));
  }
}

// ----------------------------------------------------------------------
extern "C" void kernel_launch(void* const* d_in, const int* in_sizes, int n_in,
                              void* d_out, int out_size, void* d_ws, size_t ws_size,
                              hipStream_t stream)
{
  const float* H     = (const float*)d_in[0];
  const float* A1    = (const float*)d_in[1];
  const float* A2    = (const float*)d_in[2];
  const float* V     = (const float*)d_in[3];
  const float* few   = (const float*)d_in[4];
  const float* mup   = (const float*)d_in[5];
  const float* devp  = (const float*)d_in[6];
  const float* gW    = (const float*)d_in[7];
  const float* gA    = (const float*)d_in[8];
  const float* g1    = (const float*)d_in[9];
  const float* g2w   = (const float*)d_in[10];
  const float* g2b   = (const float*)d_in[11];
  const float* w0 = (const float*)d_in[12]; const float* b0 = (const float*)d_in[13];
  const float* w1 = (const float*)d_in[14]; const float* b1 = (const float*)d_in[15];
  const float* w2 = (const float*)d_in[16]; const float* b2 = (const float*)d_in[17];
  const float* w3 = (const float*)d_in[18]; const float* b3 = (const float*)d_in[19];
  float* outp = (float*)d_out;

  float* ws = (float*)d_ws;
  // fixed layout (floats)
  float* x      = ws;                    // 573440
  float* xn     = ws + 573440;           // 573440
  float* h      = ws + 1146880;          // 589824 (B*N*72)
  short* hb16   = (short*)(ws + 1736704);  // B*N*96 bf16
  short* hAb16  = (short*)(ws + 2129920);
  short* hT16   = (short*)(ws + 2523136);  // B*96*N bf16
  float* M1   = ws + 2916352;
  float* S1   = ws + 2924544;
  float* M2   = ws + 2932736;
  float* S2   = ws + 2940928;
  float* M1p  = ws + 2949120;
  float* S1p  = ws + 2981888;
  float* M2p  = ws + 3014656;
  float* S2p  = ws + 3047424;
  float* pooled = ws + 3080192;          // 576
  float* hp1p = ws + 3080768;            // JC*8*1024*80
  // JC chosen to fit ws
  int JC = 4;
  while (JC > 1 && (size_t)(3080768 + (size_t)JC * 1310720) * 4 > ws_size) JC >>= 1;
  if ((size_t)(3080768 + (size_t)JC * 1310720) * 4 > ws_size) return;  // can't run
  float* hp2p = hp1p + (size_t)JC * 655360;
  const int njt = (N_ / 32) / JC;

  const int ROWS = B_ * N_;
  featem_kernel<<<ROWS, 128, 0, stream>>>(H, few, x);

  float* xcur = x;
  float* xnxt = xn;
  for (int k = 0; k < 4; k++) {
    const float* Wk  = gW  + (size_t)k * D_ * D_;
    const float* Ak  = gA  + (size_t)k * D_ * D_;
    const float* g1k = g1  + (size_t)k * D_;
    const float* g2k = g2w + (size_t)k * D_;
    const float* gbk = g2b + k;
    gatmm0_kernel<<<ROWS, 128, 0, stream>>>(xcur, Wk, h, hb16);
    gatmm1_kernel<<<ROWS, 128, 0, stream>>>(h, Ak, hAb16);
    transpose_kernel<<<dim3(N_ / 64, B_), 256, 0, stream>>>(h, hT16);
    pass1_mfma<<<dim3(32, 4, B_), 256, 0, stream>>>(hb16, hAb16, A1, A2, mup, devp,
                                                    M1p, S1p, M2p, S2p);
    finalize_kernel<<<(B_ * N_ + 255) / 256, 256, 0, stream>>>(M1p, S1p, M2p, S2p,
                                                               M1, S1, M2, S2);
    pass2_mfma<<<dim3(32, JC, B_), 256, 0, stream>>>(hb16, hAb16, hT16, A1, A2, mup, devp,
                                                     M1, S1, M2, S2, hp1p, hp2p, njt);
    combine_kernel<<<ROWS, 64, 0, stream>>>(xcur, hp1p, hp2p, JC, g1k, g2k, gbk, xnxt);
    float* tmp = xcur; xcur = xnxt; xnxt = tmp;
  }

  pool_kernel<<<dim3(D_, B_), 256, 0, stream>>>(xcur, V, pooled);
  fc_kernel<<<1, 256, 0, stream>>>(pooled, w0, b0, w1, b1, w2, b2, w3, b3, outp);
}

// Round 3
// 381.070 us; speedup vs baseline: 5.1941x; 1.3205x over previous
//
#include <hip/hip_runtime.h>

#define B_   8
#define N_   1024
#define F0_  56
#define D_   70
#define DK_  96      // bf16 K-padded row stride (3 x 32)
#define DFC_ 128
#define NEG_BIG (-9e15f)

typedef __attribute__((ext_vector_type(8))) short bf16x8;
typedef __attribute__((ext_vector_type(4))) float f32x4;
typedef unsigned short ushortT;

__device__ __forceinline__ short f2bf(float x) {
  unsigned u = __builtin_bit_cast(unsigned, x);
  u += 0x7FFF + ((u >> 16) & 1);
  return (short)(u >> 16);
}
__device__ __forceinline__ float bfdec(unsigned u16bits) {
  unsigned v = u16bits << 16;
  return __builtin_bit_cast(float, v);
}

// ---------------------------------------------------------------- featem
__global__ __launch_bounds__(128) void featem_kernel(
    const float* __restrict__ H, const float* __restrict__ W, float* __restrict__ x)
{
  const int r = blockIdx.x, t = threadIdx.x;
  __shared__ float row[F0_];
  if (t < F0_) row[t] = H[(size_t)r * F0_ + t];
  __syncthreads();
  if (t < D_) {
    float a = 0.f;
#pragma unroll 8
    for (int m = 0; m < F0_; m++) a += row[m] * W[t * F0_ + m];
    x[(size_t)r * D_ + t] = a;
  }
}

// -------------------------------------------------- adjacency pre-pack
// u16: bits[15:1] = bf16(rbf+A1) with mantissa LSB dropped, bit0 = (A1>0)
__global__ __launch_bounds__(256) void prep_adj(
    const float* __restrict__ A1, const float* __restrict__ A2,
    const float* __restrict__ mup, const float* __restrict__ devp,
    ushortT* __restrict__ adjp)
{
  const size_t idx = ((size_t)blockIdx.x * 256 + threadIdx.x) * 4;
  const float4 a1 = *(const float4*)(A1 + idx);
  const float4 a2 = *(const float4*)(A2 + idx);
  const float mu = mup[0], idev = 1.0f / devp[0];
  ushortT out[4];
  const float a1v[4] = {a1.x, a1.y, a1.z, a1.w};
  const float a2v[4] = {a2.x, a2.y, a2.z, a2.w};
#pragma unroll
  for (int k = 0; k < 4; k++) {
    const float rbf = (a2v[k] <= 10.f) ? __expf(-(a2v[k] - mu) * (a2v[k] - mu) * idev) : 0.f;
    const float adj1 = rbf + a1v[k];
    ushortT u = ((ushortT)f2bf(adj1)) & 0xFFFE;
    if (a1v[k] > 0.f) u |= 1;
    out[k] = u;
  }
  *(uint2*)(adjp + idx) = *(uint2*)out;
}

// ------------------------------------- fused h / hA / hT  (per 16 rows)
#define GROWS 16
__global__ __launch_bounds__(256) void gatmm_fused(
    const float* __restrict__ x, const float* __restrict__ W, const float* __restrict__ A,
    short* __restrict__ hb16, short* __restrict__ hAb16, short* __restrict__ hT)
{
  __shared__ float sW[D_ * D_];
  __shared__ float sA[D_ * D_];
  __shared__ float sx[GROWS * D_];
  __shared__ float sh[GROWS * D_];
  const int tid = threadIdx.x;
  const int r0 = blockIdx.x * GROWS;
  const int b = r0 >> 10, n0 = r0 & (N_ - 1);
  for (int i = tid; i < D_ * D_; i += 256) { sW[i] = W[i]; sA[i] = A[i]; }
  for (int i = tid; i < GROWS * D_; i += 256) sx[i] = x[(size_t)r0 * D_ + i];
  __syncthreads();
  for (int idx = tid; idx < GROWS * D_; idx += 256) {
    const int rr = idx / D_, d = idx - rr * D_;
    float a = 0.f;
#pragma unroll 7
    for (int m = 0; m < D_; m++) a += sx[rr * D_ + m] * sW[d * D_ + m];
    sh[idx] = a;
  }
  __syncthreads();
  for (int idx = tid; idx < GROWS * DK_; idx += 256) {
    const int rr = idx / DK_, d = idx - rr * DK_;
    const float v = (d < D_) ? sh[rr * D_ + d] : 0.f;
    const short u = f2bf(v);
    hb16[(size_t)(r0 + rr) * DK_ + d] = u;
    hT[((size_t)b * DK_ + d) * N_ + n0 + rr] = u;
  }
  for (int idx = tid; idx < GROWS * DK_; idx += 256) {
    const int rr = idx / DK_, d = idx - rr * DK_;
    float a = 0.f;
    if (d < D_) {
#pragma unroll 7
      for (int m = 0; m < D_; m++) a += sh[rr * D_ + m] * sA[m * D_ + d];
    }
    hAb16[(size_t)(r0 + rr) * DK_ + d] = f2bf(a);
  }
}

// ------------------------------------------- pass1: online softmax stats (MFMA)
template<bool PRE>
__global__ __launch_bounds__(256) void pass1_mfma(
    const ushortT* __restrict__ adjp,
    const short* __restrict__ hb16, const short* __restrict__ hAb16,
    const float* __restrict__ A1, const float* __restrict__ A2,
    const float* __restrict__ mup, const float* __restrict__ devp,
    float* __restrict__ M1p, float* __restrict__ S1p,
    float* __restrict__ M2p, float* __restrict__ S2p)
{
  const int jt = blockIdx.x, ic = blockIdx.y, b = blockIdx.z;
  const int tid = threadIdx.x, w = tid >> 6, lane = tid & 63;
  const int lr = lane & 15, kg = lane >> 4;
  const int ih = w >> 1, jh = w & 1;
  const int j0 = jt * 32;
  const short* hb  = hb16  + (size_t)b * N_ * DK_;
  const short* hAb = hAb16 + (size_t)b * N_ * DK_;

  bf16x8 b_h[3], b_hA[3];
  {
    const short* p = hb  + (size_t)(j0 + jh * 16 + lr) * DK_ + kg * 8;
    const short* q = hAb + (size_t)(j0 + jh * 16 + lr) * DK_ + kg * 8;
#pragma unroll
    for (int ks = 0; ks < 3; ks++) {
      b_h[ks]  = *(const bf16x8*)(p + ks * 32);
      b_hA[ks] = *(const bf16x8*)(q + ks * 32);
    }
  }
  const int jcol = j0 + jh * 16 + lr;
  float M1r = -3.0e38f, S1r = 0.f, M2r = -3.0e38f, S2r = 0.f;
  const int ibase = ic * (N_ / 4);
  float mu = 0.f, idev = 0.f;
  if (!PRE) { mu = mup[0]; idev = 1.0f / devp[0]; }

  for (int itl = 0; itl < N_ / 4; itl += 32) {
    const int i0 = ibase + itl + ih * 16;
    const short* pa = hAb + (size_t)(i0 + lr) * DK_ + kg * 8;
    const short* ph = hb  + (size_t)(i0 + lr) * DK_ + kg * 8;
    bf16x8 a_hA[3], a_h[3];
#pragma unroll
    for (int ks = 0; ks < 3; ks++) {
      a_hA[ks] = *(const bf16x8*)(pa + ks * 32);
      a_h[ks]  = *(const bf16x8*)(ph + ks * 32);
    }
    bool gon1[4], gon2[4];
    if constexpr (PRE) {
      const ushortT* Ap = adjp + ((size_t)b * N_ + i0 + kg * 4) * N_ + jcol;
#pragma unroll
      for (int r = 0; r < 4; r++) {
        const ushortT u = Ap[(size_t)r * N_];
        gon1[r] = (u & 0xFFFEu) != 0; gon2[r] = (u & 1u) != 0;
      }
    } else {
      const float* A1p = A1 + ((size_t)b * N_ + i0 + kg * 4) * N_ + jcol;
      const float* A2p = A2 + ((size_t)b * N_ + i0 + kg * 4) * N_ + jcol;
#pragma unroll
      for (int r = 0; r < 4; r++) {
        const float a1 = A1p[(size_t)r * N_], a2 = A2p[(size_t)r * N_];
        gon1[r] = (a2 <= 10.f) || (a1 > 0.f); gon2[r] = a1 > 0.f;
      }
    }
    f32x4 E = {0.f, 0.f, 0.f, 0.f};
#pragma unroll
    for (int ks = 0; ks < 3; ks++)
      E = __builtin_amdgcn_mfma_f32_16x16x32_bf16(a_hA[ks], b_h[ks], E, 0, 0, 0);
#pragma unroll
    for (int ks = 0; ks < 3; ks++)
      E = __builtin_amdgcn_mfma_f32_16x16x32_bf16(a_h[ks], b_hA[ks], E, 0, 0, 0);
#pragma unroll
    for (int r = 0; r < 4; r++) {
      const float e = E[r];
      const float m1 = gon1[r] ? e : NEG_BIG;
      const float m2 = gon2[r] ? e : NEG_BIG;
      if (m1 > M1r) { S1r = S1r * __expf(M1r - m1) + 1.f; M1r = m1; } else { S1r += __expf(m1 - M1r); }
      if (m2 > M2r) { S2r = S2r * __expf(M2r - m2) + 1.f; M2r = m2; } else { S2r += __expf(m2 - M2r); }
    }
  }
#pragma unroll
  for (int off = 16; off <= 32; off <<= 1) {
    float Mo = __shfl_xor(M1r, off), So = __shfl_xor(S1r, off);
    float nM = fmaxf(M1r, Mo);
    S1r = S1r * __expf(M1r - nM) + So * __expf(Mo - nM); M1r = nM;
    Mo = __shfl_xor(M2r, off); So = __shfl_xor(S2r, off);
    nM = fmaxf(M2r, Mo);
    S2r = S2r * __expf(M2r - nM) + So * __expf(Mo - nM); M2r = nM;
  }
  __shared__ float sM[2][4][16], sS[2][4][16];
  if (lane < 16) {
    sM[0][w][lr] = M1r; sS[0][w][lr] = S1r;
    sM[1][w][lr] = M2r; sS[1][w][lr] = S2r;
  }
  __syncthreads();
  if (tid < 32) {
    const int jhh = tid >> 4, l2 = tid & 15;
    const size_t o = ((size_t)b * 4 + ic) * N_ + j0 + jhh * 16 + l2;
    {
      float Ma = sM[0][jhh][l2], Sa = sS[0][jhh][l2];
      float Mb = sM[0][2 + jhh][l2], Sb = sS[0][2 + jhh][l2];
      float nM = fmaxf(Ma, Mb);
      M1p[o] = nM; S1p[o] = Sa * __expf(Ma - nM) + Sb * __expf(Mb - nM);
    }
    {
      float Ma = sM[1][jhh][l2], Sa = sS[1][jhh][l2];
      float Mb = sM[1][2 + jhh][l2], Sb = sS[1][2 + jhh][l2];
      float nM = fmaxf(Ma, Mb);
      M2p[o] = nM; S2p[o] = Sa * __expf(Ma - nM) + Sb * __expf(Mb - nM);
    }
  }
}

// merge the 4 i-chunk partials
__global__ __launch_bounds__(256) void finalize_kernel(
    const float* __restrict__ M1p, const float* __restrict__ S1p,
    const float* __restrict__ M2p, const float* __restrict__ S2p,
    float* __restrict__ M1, float* __restrict__ S1,
    float* __restrict__ M2, float* __restrict__ S2)
{
  int idx = blockIdx.x * 256 + threadIdx.x;
  if (idx >= B_ * N_) return;
  int b = idx >> 10, k = idx & (N_ - 1);
  {
    float M = -3.0e38f, S = 0.f;
    for (int q = 0; q < 4; q++) {
      float m = M1p[((size_t)b * 4 + q) * N_ + k], s = S1p[((size_t)b * 4 + q) * N_ + k];
      float nM = fmaxf(M, m);
      S = S * __expf(M - nM) + s * __expf(m - nM); M = nM;
    }
    M1[idx] = M; S1[idx] = S;
  }
  {
    float M = -3.0e38f, S = 0.f;
    for (int q = 0; q < 4; q++) {
      float m = M2p[((size_t)b * 4 + q) * N_ + k], s = S2p[((size_t)b * 4 + q) * N_ + k];
      float nM = fmaxf(M, m);
      S = S * __expf(M - nM) + s * __expf(m - nM); M = nM;
    }
    M2[idx] = M; S2[idx] = S;
  }
}

// ------------------------------------------- pass2: E + PV via MFMA
template<bool PRE>
__global__ __launch_bounds__(256) void pass2_mfma(
    const ushortT* __restrict__ adjp,
    const short* __restrict__ hb16, const short* __restrict__ hAb16,
    const short* __restrict__ hT16,
    const float* __restrict__ A1, const float* __restrict__ A2,
    const float* __restrict__ mup, const float* __restrict__ devp,
    const float* __restrict__ M1, const float* __restrict__ S1,
    const float* __restrict__ M2, const float* __restrict__ S2,
    ushortT* __restrict__ hp1p, ushortT* __restrict__ hp2p, int njt)
{
  const int it = blockIdx.x, jc = blockIdx.y, b = blockIdx.z;
  const int tid = threadIdx.x, w = tid >> 6, lane = tid & 63;
  const int lr = lane & 15, kg = lane >> 4;
  const int ih = w >> 1, jh = w & 1;
  const int i0 = it * 32;
  const int dbase = (w & 1) * 3;

  const short* hb  = hb16  + (size_t)b * N_ * DK_;
  const short* hAb = hAb16 + (size_t)b * N_ * DK_;
  const short* hTb = hT16  + (size_t)b * DK_ * N_;

  bf16x8 a_hA[3], a_h[3];
  {
    const short* pa = hAb + (size_t)(i0 + ih * 16 + lr) * DK_ + kg * 8;
    const short* ph = hb  + (size_t)(i0 + ih * 16 + lr) * DK_ + kg * 8;
#pragma unroll
    for (int ks = 0; ks < 3; ks++) {
      a_hA[ks] = *(const bf16x8*)(pa + ks * 32);
      a_h[ks]  = *(const bf16x8*)(ph + ks * 32);
    }
  }
  float mu = 0.f, idev = 0.f;
  if (!PRE) { mu = mup[0]; idev = 1.0f / devp[0]; }
  f32x4 acc[2][3];
#pragma unroll
  for (int m = 0; m < 2; m++)
#pragma unroll
    for (int q = 0; q < 3; q++) acc[m][q] = (f32x4){0.f, 0.f, 0.f, 0.f};

  __shared__ short wlds[2][32][40];
  const int j0base = jc * njt * 32;

  for (int t = 0; t < njt; ++t) {
    const int j0 = j0base + t * 32;
    const int jcol = j0 + jh * 16 + lr;
    // ---- issue all independent global loads up front
    bf16x8 b_h[3], b_hA[3], bt[3];
    {
      const short* p = hb  + (size_t)(j0 + jh * 16 + lr) * DK_ + kg * 8;
      const short* q = hAb + (size_t)(j0 + jh * 16 + lr) * DK_ + kg * 8;
#pragma unroll
      for (int ks = 0; ks < 3; ks++) {
        b_h[ks]  = *(const bf16x8*)(p + ks * 32);
        b_hA[ks] = *(const bf16x8*)(q + ks * 32);
      }
    }
#pragma unroll
    for (int q = 0; q < 3; q++)
      bt[q] = *(const bf16x8*)(hTb + (size_t)((dbase + q) * 16 + lr) * N_ + j0 + kg * 8);

    float adj1v[4]; bool gon1[4], gon2[4];
    if constexpr (PRE) {
      const ushortT* Ap = adjp + ((size_t)b * N_ + i0 + ih * 16 + kg * 4) * N_ + jcol;
#pragma unroll
      for (int r = 0; r < 4; r++) {
        const ushortT u = Ap[(size_t)r * N_];
        adj1v[r] = bfdec(u & 0xFFFEu);
        gon1[r] = (u & 0xFFFEu) != 0; gon2[r] = (u & 1u) != 0;
      }
    } else {
      const float* A1p = A1 + ((size_t)b * N_ + i0 + ih * 16 + kg * 4) * N_ + jcol;
      const float* A2p = A2 + ((size_t)b * N_ + i0 + ih * 16 + kg * 4) * N_ + jcol;
#pragma unroll
      for (int r = 0; r < 4; r++) {
        const float a1 = A1p[(size_t)r * N_], a2 = A2p[(size_t)r * N_];
        const float rbf = (a2 <= 10.f) ? __expf(-(a2 - mu) * (a2 - mu) * idev) : 0.f;
        adj1v[r] = rbf + a1;
        gon1[r] = adj1v[r] > 0.f; gon2[r] = a1 > 0.f;
      }
    }
    const float M1j = M1[(size_t)b * N_ + jcol];
    const float is1 = 1.0f / S1[(size_t)b * N_ + jcol];
    const float M2j = M2[(size_t)b * N_ + jcol];
    const float is2 = 1.0f / S2[(size_t)b * N_ + jcol];

    f32x4 E = {0.f, 0.f, 0.f, 0.f};
#pragma unroll
    for (int ks = 0; ks < 3; ks++)
      E = __builtin_amdgcn_mfma_f32_16x16x32_bf16(a_hA[ks], b_h[ks], E, 0, 0, 0);
#pragma unroll
    for (int ks = 0; ks < 3; ks++)
      E = __builtin_amdgcn_mfma_f32_16x16x32_bf16(a_h[ks], b_hA[ks], E, 0, 0, 0);

    short w1v[4], w2v[4];
#pragma unroll
    for (int r = 0; r < 4; r++) {
      const float e = E[r];
      w1v[r] = f2bf(gon1[r] ? __expf(e - M1j) * adj1v[r] * is1 : 0.f);
      w2v[r] = f2bf(gon2[r] ? __expf(e - M2j) * is2 : 0.f);
    }
    __syncthreads();
#pragma unroll
    for (int r = 0; r < 4; r++) {
      wlds[0][ih * 16 + kg * 4 + r][jh * 16 + lr] = w1v[r];
      wlds[1][ih * 16 + kg * 4 + r][jh * 16 + lr] = w2v[r];
    }
    __syncthreads();
#pragma unroll
    for (int m = 0; m < 2; m++) {
      bf16x8 af = *(const bf16x8*)&wlds[m][ih * 16 + lr][kg * 8];
#pragma unroll
      for (int q = 0; q < 3; q++)
        acc[m][q] = __builtin_amdgcn_mfma_f32_16x16x32_bf16(af, bt[q], acc[m][q], 0, 0, 0);
    }
  }
#pragma unroll
  for (int m = 0; m < 2; m++) {
#pragma unroll
    for (int q = 0; q < 3; q++) {
      const int dt = dbase + q;
      if (dt < 5) {
        ushortT* dst = (m ? hp2p : hp1p) +
            (((size_t)jc * B_ + b) * N_ + i0 + ih * 16 + kg * 4) * 80 + dt * 16 + lr;
#pragma unroll
        for (int r = 0; r < 4; r++) dst[(size_t)r * 80] = (ushortT)f2bf(acc[m][q][r]);
      }
    }
  }
}

// ---------------------- gating + combine (+partial sum, relu), in-place x
__global__ __launch_bounds__(256) void combine_kernel(
    float* __restrict__ x,
    const ushortT* __restrict__ hp1p, const ushortT* __restrict__ hp2p, int JC,
    const float* __restrict__ g1, const float* __restrict__ g2w,
    const float* __restrict__ g2b)
{
  const int r = blockIdx.x * 4 + (threadIdx.x >> 6);
  const int t = threadIdx.x & 63;
  float s1a = 0.f, s2a = 0.f, s1b = 0.f, s2b = 0.f;
  for (int q = 0; q < JC; q++) {
    const size_t base = ((size_t)q * (B_ * N_) + r) * 80;
    s1a += bfdec(hp1p[base + t]);
    s2a += bfdec(hp2p[base + t]);
    if (t < D_ - 64) {
      s1b += bfdec(hp1p[base + 64 + t]);
      s2b += bfdec(hp2p[base + 64 + t]);
    }
  }
  const float a0 = fmaxf(s1a, 0.f), b0 = fmaxf(s2a, 0.f);
  const float a1v = fmaxf(s1b, 0.f), b1v = fmaxf(s2b, 0.f);
  float* xr = x + (size_t)r * D_;
  const float x0 = xr[t];
  float d1 = x0 * g1[t], d2 = a0 * g2w[t], d3 = b0 * g2w[t];
  float x1 = 0.f;
  if (t < D_ - 64) {
    x1 = xr[64 + t];
    d1 += x1 * g1[64 + t]; d2 += a1v * g2w[64 + t]; d3 += b1v * g2w[64 + t];
  }
#pragma unroll
  for (int off = 1; off < 64; off <<= 1) {
    d1 += __shfl_xor(d1, off);
    d2 += __shfl_xor(d2, off);
    d3 += __shfl_xor(d3, off);
  }
  const float bb = g2b[0];
  const float c1 = 1.f / (1.f + __expf(-(d1 + d2 + bb)));
  const float c2 = 1.f / (1.f + __expf(-(d1 + d3 + bb)));
  xr[t] = (c1 * x0 + (1.f - c1) * a0) - (c2 * x0 + (1.f - c2) * b0);
  if (t < D_ - 64)
    xr[64 + t] = (c1 * x1 + (1.f - c1) * a1v) - (c2 * x1 + (1.f - c2) * b1v);
}

// ------------------------------------------- masked sum pool over N
__global__ __launch_bounds__(256) void pool_kernel(
    const float* __restrict__ x, const float* __restrict__ V, float* __restrict__ pooled)
{
  const int d = blockIdx.x, b = blockIdx.y, t = threadIdx.x;
  const float* xb = x + (size_t)b * N_ * D_;
  const float* Vb = V + (size_t)b * N_;
  float s = 0.f;
  for (int n = t; n < N_; n += 256) s += xb[(size_t)n * D_ + d] * Vb[n];
#pragma unroll
  for (int off = 32; off >= 1; off >>= 1) s += __shfl_down(s, off);
  __shared__ float red[4];
  if ((t & 63) == 0) red[t >> 6] = s;
  __syncthreads();
  if (t == 0) pooled[b * D_ + d] = red[0] + red[1] + red[2] + red[3];
}

// ------------------------------------------- MLP head (single block)
__global__ __launch_bounds__(256) void fc_kernel(
    const float* __restrict__ pooled,
    const float* __restrict__ w0, const float* __restrict__ b0,
    const float* __restrict__ w1, const float* __restrict__ b1,
    const float* __restrict__ w2, const float* __restrict__ b2,
    const float* __restrict__ w3, const float* __restrict__ b3,
    float* __restrict__ out)
{
  __shared__ float pin[B_][D_];
  __shared__ float bufA[B_][DFC_], bufB[B_][DFC_];
  const int t = threadIdx.x;
  for (int idx = t; idx < B_ * D_; idx += 256) pin[idx / D_][idx % D_] = pooled[idx];
  __syncthreads();
  for (int idx = t; idx < B_ * DFC_; idx += 256) {
    int r = idx >> 7, o = idx & 127;
    float a = b0[o];
    for (int m = 0; m < D_; m++) a += pin[r][m] * w0[o * D_ + m];
    bufA[r][o] = fmaxf(a, 0.f);
  }
  __syncthreads();
  for (int idx = t; idx < B_ * DFC_; idx += 256) {
    int r = idx >> 7, o = idx & 127;
    float a = b1[o];
    for (int m = 0; m < DFC_; m++) a += bufA[r][m] * w1[o * DFC_ + m];
    bufB[r][o] = fmaxf(a, 0.f);
  }
  __syncthreads();
  for (int idx = t; idx < B_ * DFC_; idx += 256) {
    int r = idx >> 7, o = idx & 127;
    float a = b2[o];
    for (int m = 0; m < DFC_; m++) a += bufB[r][m] * w2[o * DFC_ + m];
    bufA[r][o] = fmaxf(a, 0.f);
  }
  __syncthreads();
  if (t < B_) {
    float a = b3[0];
    for (int m = 0; m < DFC_; m++) a += bufA[t][m] * w3[m];
    out[t] = 1.f / (1.f + __expf(-a));
  }
}

// ----------------------------------------------------------------------
extern "C" void kernel_launch(void* const* d_in, const int* in_sizes, int n_in,
                              void* d_out, int out_size, void* d_ws, size_t ws_size,
                              hipStream_t stream)
{
  const float* H     = (const float*)d_in[0];
  const float* A1    = (const float*)d_in[1];
  const float* A2    = (const float*)d_in[2];
  const float* V     = (const float*)d_in[3];
  const float* few   = (const float*)d_in[4];
  const float* mup   = (const float*)d_in[5];
  const float* devp  = (const float*)d_in[6];
  const float* gW    = (const float*)d_in[7];
  const float* gA    = (const float*)d_in[8];
  const float* g1    = (const float*)d_in[9];
  const float* g2w   = (const float*)d_in[10];
  const float* g2b   = (const float*)d_in[11];
  const float* w0 = (const float*)d_in[12]; const float* b0 = (const float*)d_in[13];
  const float* w1 = (const float*)d_in[14]; const float* b1 = (const float*)d_in[15];
  const float* w2 = (const float*)d_in[16]; const float* b2 = (const float*)d_in[17];
  const float* w3 = (const float*)d_in[18]; const float* b3 = (const float*)d_in[19];
  float* outp = (float*)d_out;

  float* ws = (float*)d_ws;
  // fixed layout (float offsets)
  float* x     = ws;                         // 573440
  short* hb16  = (short*)(ws + 573440);      // B*N*96 bf16
  short* hAb16 = (short*)(ws + 966656);
  short* hT16  = (short*)(ws + 1359872);     // B*96*N bf16
  float* M1  = ws + 1753088;
  float* S1  = ws + 1761280;
  float* M2  = ws + 1769472;
  float* S2  = ws + 1777664;
  float* M1p = ws + 1785856;
  float* S1p = ws + 1818624;
  float* M2p = ws + 1851392;
  float* S2p = ws + 1884160;
  float* pooled = ws + 1916928;              // 576 -> end 1917504
  ushortT* adjp = (ushortT*)(ws + 1917504);  // 8M u16 = 4194304 f (PRE only)

  auto need = [](bool pre, int jc) -> size_t {
    return (size_t)((pre ? 6111808u : 1917504u) + (size_t)jc * 655360u) * 4u;
  };
  bool PRE; int JC;
  if      (need(true, 4) <= ws_size) { PRE = true;  JC = 4; }
  else if (need(true, 2) <= ws_size) { PRE = true;  JC = 2; }
  else if (need(true, 1) <= ws_size) { PRE = true;  JC = 1; }
  else if (need(false,4) <= ws_size) { PRE = false; JC = 4; }
  else if (need(false,2) <= ws_size) { PRE = false; JC = 2; }
  else if (need(false,1) <= ws_size) { PRE = false; JC = 1; }
  else return;
  ushortT* hp1p = (ushortT*)(ws + (PRE ? 6111808u : 1917504u));
  ushortT* hp2p = hp1p + (size_t)JC * 655360u;
  const int njt = (N_ / 32) / JC;

  const int ROWS = B_ * N_;
  featem_kernel<<<ROWS, 128, 0, stream>>>(H, few, x);
  if (PRE)
    prep_adj<<<(B_ * N_ * N_ / 4) / 256, 256, 0, stream>>>(A1, A2, mup, devp, adjp);

  for (int k = 0; k < 4; k++) {
    const float* Wk  = gW  + (size_t)k * D_ * D_;
    const float* Ak  = gA  + (size_t)k * D_ * D_;
    const float* g1k = g1  + (size_t)k * D_;
    const float* g2k = g2w + (size_t)k * D_;
    const float* gbk = g2b + k;
    gatmm_fused<<<ROWS / GROWS, 256, 0, stream>>>(x, Wk, Ak, hb16, hAb16, hT16);
    if (PRE)
      pass1_mfma<true><<<dim3(32, 4, B_), 256, 0, stream>>>(adjp, hb16, hAb16, A1, A2,
                                                            mup, devp, M1p, S1p, M2p, S2p);
    else
      pass1_mfma<false><<<dim3(32, 4, B_), 256, 0, stream>>>(adjp, hb16, hAb16, A1, A2,
                                                             mup, devp, M1p, S1p, M2p, S2p);
    finalize_kernel<<<(B_ * N_ + 255) / 256, 256, 0, stream>>>(M1p, S1p, M2p, S2p,
                                                               M1, S1, M2, S2);
    if (PRE)
      pass2_mfma<true><<<dim3(32, JC, B_), 256, 0, stream>>>(adjp, hb16, hAb16, hT16,
          A1, A2, mup, devp, M1, S1, M2, S2, hp1p, hp2p, njt);
    else
      pass2_mfma<false><<<dim3(32, JC, B_), 256, 0, stream>>>(adjp, hb16, hAb16, hT16,
          A1, A2, mup, devp, M1, S1, M2, S2, hp1p, hp2p, njt);
    combine_kernel<<<ROWS / 4, 256, 0, stream>>>(x, hp1p, hp2p, JC, g1k, g2k, gbk);
  }

  pool_kernel<<<dim3(D_, B_), 256, 0, stream>>>(x, V, pooled);
  fc_kernel<<<1, 256, 0, stream>>>(pooled, w0, b0, w1, b1, w2, b2, w3, b3, outp);
}